// Round 7
// baseline (255.771 us; speedup 1.0000x reference)
//
#include <hip/hip_runtime.h>
#include <math.h>

// Problem constants: B=64, T=2000, V=29, L=200
#define Bn 64
#define Tn 2000
#define Vn 29
#define Ln 200
#define Sn 401              // 2L+1 lattice states
#define BLANKC 28
#define EPSF  1e-7f
#define CHUNK 128           // time steps of linear probs per LDS buffer
#define TSTR  132           // floats per symbol row (128 + pad, 16B-aligned quads)
#define SENT  (-(1 << 20))  // exponent sentinel for all-zero lanes
#define LN2F  0.69314718055994531f

__device__ __forceinline__ float getc(const float4& v, int u) {
    return u == 0 ? v.x : u == 1 ? v.y : u == 2 ? v.z : v.w;
}
__device__ __forceinline__ float bpermf(int addr, float x) {
    return __int_as_float(__builtin_amdgcn_ds_bpermute(addr, __float_as_int(x)));
}

// ---------- forward round (state set *_f). Order: align, DP, fmax, SEND
// (bpermutes), prefetch, renorm — sends early so the B-chain hides their latency.
#define ROUNDF(T0, PIN, POUT, PC, TOFFN) do {                                    \
  const int EeffF_ = zf_f ? SENT : E_f;                                          \
  const int EnF_   = max(EeffF_, Enb_f);                                         \
  const int dbF_ = Enb_f - EnF_, dnF_ = E_f - EnF_;                              \
  float w[16];                                                                   \
  _Pragma("unroll") for (int k = 0; k < 8; ++k) w[k]     = ldexpf(nb_f[k], dbF_);\
  _Pragma("unroll") for (int k = 0; k < 8; ++k) w[8 + k] = ldexpf(a_f[k],  dnF_);\
  _Pragma("unroll") for (int u = 0; u < 4; ++u) {                                \
    const int t_ = (T0) + u;                                                     \
    if (t_ != 0 && t_ < TFe) {                                                   \
      _Pragma("unroll") for (int ii = 0; ii < 14 - 2 * u; ++ii) {                \
        const int i = 15 - ii;                                                   \
        if (i & 1) {                                                             \
          const int kk = (i - 3) >> 1;                                           \
          w[i] = (fmaf(skOdd[kk], w[i-2], w[i]) + w[i-1]) * getc(PIN[kk], u);    \
        } else {                                                                 \
          w[i] = (w[i] + w[i-1]) * getc(PIN[7], u);                              \
        } } } }                                                                  \
  float mxF_ = fmaxf(fmaxf(fmaxf(w[8],w[9]),fmaxf(w[10],w[11])),                 \
                     fmaxf(fmaxf(w[12],w[13]),fmaxf(w[14],w[15])));              \
  const bool z2F_ = !(mxF_ > 0.f);                                               \
  _Pragma("unroll") for (int k = 0; k < 8; ++k) nb_f[k] = bpermf(pup, w[8 + k]); \
  Enb_f = __builtin_amdgcn_ds_bpermute(pup, z2F_ ? SENT : EnF_);                 \
  { const int tf_ = (TOFFN) > (CHUNK-4) ? (CHUNK-4) : (TOFFN);                   \
    _Pragma("unroll") for (int kk = 0; kk < 7; ++kk)                             \
      POUT[kk] = *(const float4*)((PC) + soffF[kk] + tf_);                       \
    POUT[7] = *(const float4*)((PC) + BLANKC * TSTR + tf_); }                    \
  if (lane == 0) {                                                               \
    _Pragma("unroll") for (int k = 0; k < 8; ++k) nb_f[k] = 0.f;                 \
    Enb_f = SENT; }                                                              \
  int eF_; (void)frexpf(mxF_, &eF_);                                             \
  _Pragma("unroll") for (int k = 0; k < 8; ++k) a_f[k] = ldexpf(w[8 + k], -eF_); \
  E_f = EnF_ + eF_; zf_f = z2F_;                                                 \
} while (0)

// ---------- backward round (state set *_b); lane owns w[0..7], lane+1 at w[8..15]
#define ROUNDB(S0, PIN, POUT, PC, TOFFN) do {                                    \
  const int EeffB_ = zf_b ? SENT : E_b;                                          \
  const int EnB_   = max(EeffB_, Enb_b);                                         \
  const int dbB_ = Enb_b - EnB_, dnB_ = E_b - EnB_;                              \
  float w[16];                                                                   \
  _Pragma("unroll") for (int k = 0; k < 8; ++k) w[k]     = ldexpf(a_b[k],  dnB_);\
  _Pragma("unroll") for (int k = 0; k < 8; ++k) w[8 + k] = ldexpf(nb_b[k], dbB_);\
  _Pragma("unroll") for (int u = 0; u < 4; ++u) {                                \
    const int s_ = (S0) + u;                                                     \
    if (s_ < TBe) {                                                              \
      float qq[16];                                                              \
      _Pragma("unroll") for (int j = 0; j < 16; ++j) {                           \
        if (j < 16 - 2 * u)                                                      \
          qq[j] = w[j] * ((j & 1) ? getc(PIN[(j-1)>>1], u) : getc(PIN[8], u));   \
        else qq[j] = 0.f; }                                                      \
      _Pragma("unroll") for (int i = 0; i < 14; ++i) {                           \
        if (i < 14 - 2 * u) {                                                    \
          if (i & 1) w[i] = fmaf(skB[(i-1)>>1], qq[i+2], qq[i]) + qq[i+1];       \
          else       w[i] = qq[i] + qq[i+1];                                     \
        } } } }                                                                  \
  float mxB_ = fmaxf(fmaxf(fmaxf(w[0],w[1]),fmaxf(w[2],w[3])),                   \
                     fmaxf(fmaxf(w[4],w[5]),fmaxf(w[6],w[7])));                  \
  const bool z2B_ = !(mxB_ > 0.f);                                               \
  _Pragma("unroll") for (int k = 0; k < 8; ++k) nb_b[k] = bpermf(pdn, w[k]);     \
  Enb_b = __builtin_amdgcn_ds_bpermute(pdn, z2B_ ? SENT : EnB_);                 \
  { const int tf_ = (TOFFN) > (CHUNK-4) ? (CHUNK-4) : (TOFFN);                   \
    _Pragma("unroll") for (int m = 0; m < 8; ++m)                                \
      POUT[m] = *(const float4*)((PC) + soffB[m] + tf_);                         \
    POUT[8] = *(const float4*)((PC) + BLANKC * TSTR + tf_); }                    \
  if (lane == 63) {                                                              \
    _Pragma("unroll") for (int k = 0; k < 8; ++k) nb_b[k] = 0.f;                 \
    Enb_b = SENT; }                                                              \
  int eB_; (void)frexpf(mxB_, &eB_);                                             \
  _Pragma("unroll") for (int k = 0; k < 8; ++k) a_b[k] = ldexpf(w[k], -eB_);     \
  E_b = EnB_ + eB_; zf_b = z2B_;                                                 \
} while (0)

__global__ __launch_bounds__(128, 1)
void ctc_dual_kernel(const float* __restrict__ logits,
                     const int*   __restrict__ labels,
                     const int*   __restrict__ input_length,
                     const int*   __restrict__ label_length,
                     const int*   __restrict__ mts_ptr,
                     float*       __restrict__ out)
{
    __shared__ __align__(16) float PFb[2][Vn * TSTR];   // fwd prob dbuf
    __shared__ __align__(16) float PBb[2][Vn * TSTR];   // bwd prob dbuf (time-reversed)

    const int b    = blockIdx.x;
    const int tid  = threadIdx.x;
    const int wid  = tid >> 6;    // 0: dual DP (fwd+bwd), 1: staging (both dirs)
    const int lane = tid & 63;
    const float* lg  = logits + (size_t)b * Tn * Vn;
    const int*   lab = labels + b * Ln;

    const int mts = *mts_ptr;
    const int ctc_len = (int)floorf((float)(input_length[b] * Tn) / (float)mts);
    const int tend = min(max(ctc_len, 1), Tn);
    const int tm   = (tend - 1) >> 1;      // meeting point
    const int TFe  = tm + 1;               // fwd consumes probs t in [0, TFe)
    const int TBe  = tend - 1 - tm;        // bwd consumes slots i=tend-1-t in [0, TBe)
    const int nchF = (TFe + CHUNK - 1) / CHUNK;
    const int nchB = (TBe + CHUNK - 1) / CHUNK;   // <= nchF

    const int pup = ((lane - 1) & 63) << 2;   // bpermute byte addr: lane-1
    const int pdn = ((lane + 1) & 63) << 2;   // lane+1

    // ---- fwd metadata: window pos i=2kk+3, state s = 8*lane-8+i ----
    int soffF[7]; float skOdd[7];
    #pragma unroll
    for (int kk = 0; kk < 7; ++kk) {
        const int s = 8 * lane - 5 + 2 * kk;
        int e = BLANKC; float sk = 0.f;
        if (s >= 0 && s < Sn) {
            const int li = (s - 1) >> 1;
            e = lab[li];
            if (s >= 3 && e != lab[li - 1]) sk = 1.f;
        }
        soffF[kk] = e * TSTR; skOdd[kk] = sk;
    }
    // ---- bwd metadata: pos j=2m+1, state s = 8*lane+j ----
    int soffB[8]; float skB[7];
    #pragma unroll
    for (int m = 0; m < 8; ++m) {
        const int s = 8 * lane + 2 * m + 1;
        soffB[m] = ((s < Sn) ? lab[(s - 1) >> 1] : BLANKC) * TSTR;
    }
    #pragma unroll
    for (int m = 0; m < 7; ++m) {
        const int s = 8 * lane + 2 * m + 3;
        float sk = 0.f;
        if (s >= 3 && s < Sn) {
            const int li = (s - 1) >> 1;
            if (lab[li] != lab[li - 1]) sk = 1.f;
        }
        skB[m] = sk;
    }

    // staging: linear probs (softmax + eps), transposed [v][slot]
    auto srow = [&](const float* row, float* Pb, int i) {
        float x[Vn]; float mm = -INFINITY;
        #pragma unroll
        for (int v = 0; v < Vn; ++v) { x[v] = row[v]; mm = fmaxf(mm, x[v]); }
        float z = 0.f;
        #pragma unroll
        for (int v = 0; v < Vn; ++v) { x[v] = __expf(x[v] - mm); z += x[v]; }
        const float rz = 1.0f / z;
        #pragma unroll
        for (int v = 0; v < Vn; ++v) Pb[v * TSTR + i] = x[v] * rz + EPSF;
    };
    auto stageF = [&](int c) {
        const int base = c * CHUNK;
        const int fill = min(CHUNK, TFe - base);
        float* Pb = PFb[c & 1];
        for (int i = lane; i < fill; i += 64)
            srow(lg + (size_t)(base + i) * Vn, Pb, i);
    };
    auto stageB = [&](int c) {
        const int base = c * CHUNK;
        const int fill = min(CHUNK, TBe - base);
        float* Pb = PBb[c & 1];
        for (int i = lane; i < fill; i += 64)
            srow(lg + (size_t)(tend - 1 - (base + i)) * Vn, Pb, i);
    };

    if (wid == 0) stageF(0);
    else if (TBe > 0) stageB(0);
    __syncthreads();

    // dual per-lane BFP state
    float a_f[8] = {0.f,0.f,0.f,0.f,0.f,0.f,0.f,0.f};
    float a_b[8] = {0.f,0.f,0.f,0.f,0.f,0.f,0.f,0.f};
    float nb_f[8], nb_b[8];
    int   E_f = 0, Enb_f = SENT, E_b = 0, Enb_b = SENT;
    bool  zf_f = true, zf_b = true;
    float4 qAf[8], qBf[8], qAb[9], qBb[9];

    if (wid == 0) {
        __builtin_amdgcn_s_setprio(1);
        // fwd init: alpha0 on states 0,1 (lane 0)
        if (lane == 0) {
            a_f[0] = PFb[0][BLANKC * TSTR];
            a_f[1] = PFb[0][soffF[3]];      // lane0 kk=3 -> s=1 -> lab[0]
        }
        zf_f = (lane != 0);
        #pragma unroll
        for (int k = 0; k < 8; ++k) nb_f[k] = bpermf(pup, a_f[k]);
        Enb_f = __builtin_amdgcn_ds_bpermute(pup, zf_f ? SENT : 0);
        if (lane == 0) {
            #pragma unroll
            for (int k = 0; k < 8; ++k) nb_f[k] = 0.f;
            Enb_f = SENT;
        }
        // bwd init: beta_{tend-1} = 1 on states 2ll, 2ll-1 (0.5 * 2^1)
        const int ll = label_length[b];
        const int s1 = 2 * ll, s2 = max(2 * ll - 1, 0);
        #pragma unroll
        for (int k = 0; k < 8; ++k) {
            const int s = 8 * lane + k;
            a_b[k] = (s == s1 || s == s2) ? 0.5f : 0.f;
        }
        E_b  = 1;
        zf_b = !(((s1 >> 3) == lane) || ((s2 >> 3) == lane));
        #pragma unroll
        for (int k = 0; k < 8; ++k) nb_b[k] = bpermf(pdn, a_b[k]);
        Enb_b = __builtin_amdgcn_ds_bpermute(pdn, zf_b ? SENT : E_b);
        if (lane == 63) {
            #pragma unroll
            for (int k = 0; k < 8; ++k) nb_b[k] = 0.f;
            Enb_b = SENT;
        }
    }

    for (int c = 0; c < nchF; ++c) {
        if (wid == 1) {
            if (c + 1 < nchF) stageF(c + 1);
            if (c + 1 < nchB) stageB(c + 1);
        } else {
            float* PcF = PFb[c & 1];
            float* PcB = PBb[c & 1];
            const int rb  = c * CHUNK;
            const int rcF = min(CHUNK, TFe - rb);
            const int rcB = (c < nchB) ? min(CHUNK, TBe - rb) : 0;
            const int nr  = (max(rcF, rcB) + 3) >> 2;

            // cold loads for round 0 of this chunk
            #pragma unroll
            for (int kk = 0; kk < 7; ++kk)
                qAf[kk] = *(const float4*)(PcF + soffF[kk]);
            qAf[7] = *(const float4*)(PcF + BLANKC * TSTR);
            #pragma unroll
            for (int m = 0; m < 8; ++m)
                qAb[m] = *(const float4*)(PcB + soffB[m]);
            qAb[8] = *(const float4*)(PcB + BLANKC * TSTR);

            // interleaved fwd/bwd rounds; guarded dummy tails are idempotent
            for (int jj = 0; jj < nr; jj += 2) {
                ROUNDF(rb + 4 * jj,       qAf, qBf, PcF, 4 * (jj + 1));
                ROUNDB(rb + 4 * jj,       qAb, qBb, PcB, 4 * (jj + 1));
                ROUNDF(rb + 4 * (jj + 1), qBf, qAf, PcF, 4 * (jj + 2));
                ROUNDB(rb + 4 * (jj + 1), qBb, qAb, PcB, 4 * (jj + 2));
            }
        }
        __syncthreads();
    }

    // readout: loss = -log sum_s alpha_tm[s] * beta_tm[s] — all lane-local now
    if (wid == 0) {
        float v = 0.f;
        #pragma unroll
        for (int k = 0; k < 8; ++k) v = fmaf(a_f[k], a_b[k], v);
        const bool val = (v > 0.f);
        const int  el  = E_f + E_b;
        int em = val ? el : -(1 << 28);
        #pragma unroll
        for (int off = 1; off < 64; off <<= 1)
            em = max(em, __shfl_xor(em, off, 64));
        float sv = val ? ldexpf(v, el - em) : 0.f;
        #pragma unroll
        for (int off = 1; off < 64; off <<= 1)
            sv += __shfl_xor(sv, off, 64);
        if (lane == 0) out[b] = -(__logf(sv) + (float)em * LN2F);
    }
}

extern "C" void kernel_launch(void* const* d_in, const int* in_sizes, int n_in,
                              void* d_out, int out_size, void* d_ws, size_t ws_size,
                              hipStream_t stream) {
    const float* logits       = (const float*)d_in[0];
    const int*   labels       = (const int*)d_in[1];
    const int*   input_length = (const int*)d_in[2];
    const int*   label_length = (const int*)d_in[3];
    const int*   mts          = (const int*)d_in[4];
    float* out = (float*)d_out;

    ctc_dual_kernel<<<Bn, 128, 0, stream>>>(logits, labels, input_length,
                                            label_length, mts, out);
}

// Round 8
// 154.920 us; speedup vs baseline: 1.6510x; 1.6510x over previous
//
#include <hip/hip_runtime.h>
#include <math.h>

// Problem constants: B=64, T=2000, V=29, L=200
#define Bn 64
#define Tn 2000
#define Vn 29
#define Ln 200
#define Sn 401              // 2L+1 lattice states
#define BLANKC 28
#define EPSF  1e-7f
#define CHUNK 128           // time steps of linear probs per LDS buffer
#define TSTR  132           // floats per symbol row (128 + pad, 16B-aligned quads)
#define SENT  (-(1 << 20))  // exponent sentinel for all-zero lanes
#define LN2F  0.69314718055994531f

__device__ __forceinline__ float getc(const float4& v, int u) {
    return u == 0 ? v.x : u == 1 ? v.y : u == 2 ? v.z : v.w;
}
__device__ __forceinline__ float bpermf(int addr, float x) {
    return __int_as_float(__builtin_amdgcn_ds_bpermute(addr, __float_as_int(x)));
}
// 2^d for d <= 0 (flush to 0 when unrepresentable — desired semantics)
__device__ __forceinline__ float dscale(int d) {
    return (d >= -126) ? __int_as_float((127 + d) << 23) : 0.f;
}

// ---------- forward round (4 steps). align -> prefetch -> DP -> fmax -> sends -> renorm
#define ROUNDF(T0, PIN, POUT, PC, TOFFN) do {                                    \
  const int EeffF_ = zf_f ? SENT : E_f;                                          \
  const int EnF_   = max(EeffF_, Enb_f);                                         \
  const float sbF_ = dscale(Enb_f - EnF_), snF_ = dscale(E_f - EnF_);            \
  float w[16];                                                                   \
  _Pragma("unroll") for (int k = 0; k < 8; ++k) w[k]     = nb_f[k] * sbF_;       \
  _Pragma("unroll") for (int k = 0; k < 8; ++k) w[8 + k] = a_f[k]  * snF_;       \
  { const int tf_ = (TOFFN) > (CHUNK-4) ? (CHUNK-4) : (TOFFN);                   \
    _Pragma("unroll") for (int kk = 0; kk < 7; ++kk)                             \
      POUT[kk] = *(const float4*)((PC) + soffF[kk] + tf_);                       \
    POUT[7] = *(const float4*)((PC) + BLANKC * TSTR + tf_); }                    \
  _Pragma("unroll") for (int u = 0; u < 4; ++u) {                                \
    const int t_ = (T0) + u;                                                     \
    if (t_ != 0 && t_ < TFe) {                                                   \
      _Pragma("unroll") for (int ii = 0; ii < 14 - 2 * u; ++ii) {                \
        const int i = 15 - ii;                                                   \
        if (i & 1) {                                                             \
          const int kk = (i - 3) >> 1;                                           \
          w[i] = (fmaf(skOdd[kk], w[i-2], w[i]) + w[i-1]) * getc(PIN[kk], u);    \
        } else {                                                                 \
          w[i] = (w[i] + w[i-1]) * getc(PIN[7], u);                              \
        } } } }                                                                  \
  float mxF_ = fmaxf(fmaxf(fmaxf(w[8],w[9]),fmaxf(w[10],w[11])),                 \
                     fmaxf(fmaxf(w[12],w[13]),fmaxf(w[14],w[15])));              \
  const bool z2F_ = !(mxF_ > 0.f);                                               \
  _Pragma("unroll") for (int k = 0; k < 8; ++k) nb_f[k] = bpermf(pup, w[8 + k]); \
  Enb_f = __builtin_amdgcn_ds_bpermute(pup, z2F_ ? SENT : EnF_);                 \
  if (lane == 0) {                                                               \
    _Pragma("unroll") for (int k = 0; k < 8; ++k) nb_f[k] = 0.f;                 \
    Enb_f = SENT; }                                                              \
  const int eF_ = ((__float_as_int(mxF_) >> 23) & 255) - 126;                    \
  const float rsF_ = __int_as_float((127 - eF_) << 23);                          \
  _Pragma("unroll") for (int k = 0; k < 8; ++k) a_f[k] = w[8 + k] * rsF_;        \
  E_f = EnF_ + eF_; zf_f = z2F_;                                                 \
} while (0)

// ---------- backward round (4 steps); lane owns w[0..7], lane+1 at w[8..15]
#define ROUNDB(S0, PIN, POUT, PC, TOFFN) do {                                    \
  const int EeffB_ = zf_b ? SENT : E_b;                                          \
  const int EnB_   = max(EeffB_, Enb_b);                                         \
  const float sbB_ = dscale(Enb_b - EnB_), snB_ = dscale(E_b - EnB_);            \
  float w[16];                                                                   \
  _Pragma("unroll") for (int k = 0; k < 8; ++k) w[k]     = a_b[k]  * snB_;       \
  _Pragma("unroll") for (int k = 0; k < 8; ++k) w[8 + k] = nb_b[k] * sbB_;       \
  { const int tf_ = (TOFFN) > (CHUNK-4) ? (CHUNK-4) : (TOFFN);                   \
    _Pragma("unroll") for (int m = 0; m < 8; ++m)                                \
      POUT[m] = *(const float4*)((PC) + soffB[m] + tf_);                         \
    POUT[8] = *(const float4*)((PC) + BLANKC * TSTR + tf_); }                    \
  _Pragma("unroll") for (int u = 0; u < 4; ++u) {                                \
    const int s_ = (S0) + u;                                                     \
    if (s_ < TBe) {                                                              \
      float qq[16];                                                              \
      _Pragma("unroll") for (int j = 0; j < 16; ++j) {                           \
        if (j < 16 - 2 * u)                                                      \
          qq[j] = w[j] * ((j & 1) ? getc(PIN[(j-1)>>1], u) : getc(PIN[8], u));   \
        else qq[j] = 0.f; }                                                      \
      _Pragma("unroll") for (int i = 0; i < 14; ++i) {                           \
        if (i < 14 - 2 * u) {                                                    \
          if (i & 1) w[i] = fmaf(skB[(i-1)>>1], qq[i+2], qq[i]) + qq[i+1];       \
          else       w[i] = qq[i] + qq[i+1];                                     \
        } } } }                                                                  \
  float mxB_ = fmaxf(fmaxf(fmaxf(w[0],w[1]),fmaxf(w[2],w[3])),                   \
                     fmaxf(fmaxf(w[4],w[5]),fmaxf(w[6],w[7])));                  \
  const bool z2B_ = !(mxB_ > 0.f);                                               \
  _Pragma("unroll") for (int k = 0; k < 8; ++k) nb_b[k] = bpermf(pdn, w[k]);     \
  Enb_b = __builtin_amdgcn_ds_bpermute(pdn, z2B_ ? SENT : EnB_);                 \
  if (lane == 63) {                                                              \
    _Pragma("unroll") for (int k = 0; k < 8; ++k) nb_b[k] = 0.f;                 \
    Enb_b = SENT; }                                                              \
  const int eB_ = ((__float_as_int(mxB_) >> 23) & 255) - 126;                    \
  const float rsB_ = __int_as_float((127 - eB_) << 23);                          \
  _Pragma("unroll") for (int k = 0; k < 8; ++k) a_b[k] = w[k] * rsB_;            \
  E_b = EnB_ + eB_; zf_b = z2B_;                                                 \
} while (0)

__global__ __launch_bounds__(256, 1)
void ctc_fb2_kernel(const float* __restrict__ logits,
                    const int*   __restrict__ labels,
                    const int*   __restrict__ input_length,
                    const int*   __restrict__ label_length,
                    const int*   __restrict__ mts_ptr,
                    float*       __restrict__ out)
{
    __shared__ __align__(16) float PFb[2][Vn * TSTR];   // fwd prob dbuf
    __shared__ __align__(16) float PBb[2][Vn * TSTR];   // bwd prob dbuf (time-reversed)

    const int b    = blockIdx.x;
    const int tid  = threadIdx.x;
    const int wid  = tid >> 6;    // 0: fwd DP, 1: bwd DP, 2: fwd stage, 3: bwd stage
    const int lane = tid & 63;
    const float* lg  = logits + (size_t)b * Tn * Vn;
    const int*   lab = labels + b * Ln;

    const int mts = *mts_ptr;
    const int ctc_len = (int)floorf((float)(input_length[b] * Tn) / (float)mts);
    const int tend = min(max(ctc_len, 1), Tn);
    const int tm   = (tend - 1) >> 1;      // meeting point
    const int TFe  = tm + 1;               // fwd consumes probs t in [0, TFe)
    const int TBe  = tend - 1 - tm;        // bwd consumes slots i=tend-1-t in [0, TBe)
    const int nchF = (TFe + CHUNK - 1) / CHUNK;
    const int nchB = (TBe + CHUNK - 1) / CHUNK;
    const int nch2 = max(nchF, nchB);

    const int pup = ((lane - 1) & 63) << 2;   // bpermute byte addr: lane-1
    const int pdn = ((lane + 1) & 63) << 2;   // lane+1

    // ---- fwd metadata ----
    int soffF[7]; float skOdd[7];
    #pragma unroll
    for (int kk = 0; kk < 7; ++kk) {
        const int s = 8 * lane - 5 + 2 * kk;
        int e = BLANKC; float sk = 0.f;
        if (s >= 0 && s < Sn) {
            const int li = (s - 1) >> 1;
            e = lab[li];
            if (s >= 3 && e != lab[li - 1]) sk = 1.f;
        }
        soffF[kk] = e * TSTR; skOdd[kk] = sk;
    }
    // ---- bwd metadata ----
    int soffB[8]; float skB[7];
    #pragma unroll
    for (int m = 0; m < 8; ++m) {
        const int s = 8 * lane + 2 * m + 1;
        soffB[m] = ((s < Sn) ? lab[(s - 1) >> 1] : BLANKC) * TSTR;
    }
    #pragma unroll
    for (int m = 0; m < 7; ++m) {
        const int s = 8 * lane + 2 * m + 3;
        float sk = 0.f;
        if (s >= 3 && s < Sn) {
            const int li = (s - 1) >> 1;
            if (lab[li] != lab[li - 1]) sk = 1.f;
        }
        skB[m] = sk;
    }

    // staging: linear probs (softmax + eps), transposed [v][slot]
    auto srow = [&](const float* row, float* Pb, int i) {
        float x[Vn]; float mm = -INFINITY;
        #pragma unroll
        for (int v = 0; v < Vn; ++v) { x[v] = row[v]; mm = fmaxf(mm, x[v]); }
        float z = 0.f;
        #pragma unroll
        for (int v = 0; v < Vn; ++v) { x[v] = __expf(x[v] - mm); z += x[v]; }
        const float rz = 1.0f / z;
        #pragma unroll
        for (int v = 0; v < Vn; ++v) Pb[v * TSTR + i] = x[v] * rz + EPSF;
    };
    auto stageF = [&](int c) {
        const int base = c * CHUNK;
        const int fill = min(CHUNK, TFe - base);
        float* Pb = PFb[c & 1];
        for (int i = lane; i < fill; i += 64)
            srow(lg + (size_t)(base + i) * Vn, Pb, i);
    };
    auto stageB = [&](int c) {
        const int base = c * CHUNK;
        const int fill = min(CHUNK, TBe - base);
        float* Pb = PBb[c & 1];
        for (int i = lane; i < fill; i += 64)
            srow(lg + (size_t)(tend - 1 - (base + i)) * Vn, Pb, i);
    };

    if (wid == 2) stageF(0);
    if (wid == 3 && TBe > 0) stageB(0);
    __syncthreads();

    // per-lane BFP state
    float a_f[8] = {0.f,0.f,0.f,0.f,0.f,0.f,0.f,0.f};
    float a_b[8] = {0.f,0.f,0.f,0.f,0.f,0.f,0.f,0.f};
    float nb_f[8], nb_b[8];
    int   E_f = 0, Enb_f = SENT, E_b = 0, Enb_b = SENT;
    bool  zf_f = true, zf_b = true;
    float4 qAf[8], qBf[8], qAb[9], qBb[9];

    if (wid == 0) {
        __builtin_amdgcn_s_setprio(1);
        if (lane == 0) {
            a_f[0] = PFb[0][BLANKC * TSTR];
            a_f[1] = PFb[0][soffF[3]];      // lane0 kk=3 -> s=1 -> lab[0]
        }
        zf_f = (lane != 0);
        #pragma unroll
        for (int k = 0; k < 8; ++k) nb_f[k] = bpermf(pup, a_f[k]);
        Enb_f = __builtin_amdgcn_ds_bpermute(pup, zf_f ? SENT : 0);
        if (lane == 0) {
            #pragma unroll
            for (int k = 0; k < 8; ++k) nb_f[k] = 0.f;
            Enb_f = SENT;
        }
    } else if (wid == 1) {
        __builtin_amdgcn_s_setprio(1);
        const int ll = label_length[b];
        const int s1 = 2 * ll, s2 = max(2 * ll - 1, 0);
        #pragma unroll
        for (int k = 0; k < 8; ++k) {
            const int s = 8 * lane + k;
            a_b[k] = (s == s1 || s == s2) ? 0.5f : 0.f;   // beta = 1 (0.5*2^1)
        }
        E_b  = 1;
        zf_b = !(((s1 >> 3) == lane) || ((s2 >> 3) == lane));
        #pragma unroll
        for (int k = 0; k < 8; ++k) nb_b[k] = bpermf(pdn, a_b[k]);
        Enb_b = __builtin_amdgcn_ds_bpermute(pdn, zf_b ? SENT : E_b);
        if (lane == 63) {
            #pragma unroll
            for (int k = 0; k < 8; ++k) nb_b[k] = 0.f;
            Enb_b = SENT;
        }
    }

    for (int c = 0; c < nch2; ++c) {
        if (wid == 2) {
            if (c + 1 < nchF) stageF(c + 1);
        } else if (wid == 3) {
            if (c + 1 < nchB) stageB(c + 1);
        } else if (wid == 0) {
            if (c < nchF) {
                float* Pc = PFb[c & 1];
                const int rbase = c * CHUNK;
                const int rcnt  = min(CHUNK, TFe - rbase);
                const int nr    = (rcnt + 3) >> 2;
                #pragma unroll
                for (int kk = 0; kk < 7; ++kk)
                    qAf[kk] = *(const float4*)(Pc + soffF[kk]);
                qAf[7] = *(const float4*)(Pc + BLANKC * TSTR);
                for (int jj = 0; jj < nr; jj += 2) {
                    ROUNDF(rbase + 4 * jj,       qAf, qBf, Pc, 4 * (jj + 1));
                    ROUNDF(rbase + 4 * (jj + 1), qBf, qAf, Pc, 4 * (jj + 2));
                }
            }
        } else {
            if (c < nchB) {
                float* Pc = PBb[c & 1];
                const int sbase = c * CHUNK;
                const int rcnt  = min(CHUNK, TBe - sbase);
                const int nr    = (rcnt + 3) >> 2;
                #pragma unroll
                for (int m = 0; m < 8; ++m)
                    qAb[m] = *(const float4*)(Pc + soffB[m]);
                qAb[8] = *(const float4*)(Pc + BLANKC * TSTR);
                for (int jj = 0; jj < nr; jj += 2) {
                    ROUNDB(sbase + 4 * jj,       qAb, qBb, Pc, 4 * (jj + 1));
                    ROUNDB(sbase + 4 * (jj + 1), qBb, qAb, Pc, 4 * (jj + 2));
                }
            }
        }
        __syncthreads();
    }

    // readout: sum_s alpha_tm[s] * beta_tm[s]  (AF/EL alias the prob buffers)
    float* AFa = PFb[0];
    int*   ELa = (int*)(PFb[0] + 512);
    float* AFb = PBb[0];
    int*   ELb = (int*)(PBb[0] + 512);

    if (wid == 0) {
        #pragma unroll
        for (int k = 0; k < 8; ++k) AFa[lane * 8 + k] = a_f[k];
        ELa[lane] = zf_f ? SENT : E_f;
    } else if (wid == 1) {
        #pragma unroll
        for (int k = 0; k < 8; ++k) AFb[lane * 8 + k] = a_b[k];
        ELb[lane] = zf_b ? SENT : E_b;
    }
    __syncthreads();

    if (wid == 0) {
        float v = 0.f;
        #pragma unroll
        for (int k = 0; k < 8; ++k)
            v = fmaf(AFa[lane * 8 + k], AFb[lane * 8 + k], v);
        const int el  = ELa[lane] + ELb[lane];
        const bool val = (v > 0.f);
        int em = val ? el : (SENT * 2);
        #pragma unroll
        for (int off = 1; off < 64; off <<= 1)
            em = max(em, __shfl_xor(em, off, 64));
        float sv = val ? ldexpf(v, el - em) : 0.f;
        #pragma unroll
        for (int off = 1; off < 64; off <<= 1)
            sv += __shfl_xor(sv, off, 64);
        if (lane == 0) out[b] = -(__logf(sv) + (float)em * LN2F);
    }
}

extern "C" void kernel_launch(void* const* d_in, const int* in_sizes, int n_in,
                              void* d_out, int out_size, void* d_ws, size_t ws_size,
                              hipStream_t stream) {
    const float* logits       = (const float*)d_in[0];
    const int*   labels       = (const int*)d_in[1];
    const int*   input_length = (const int*)d_in[2];
    const int*   label_length = (const int*)d_in[3];
    const int*   mts          = (const int*)d_in[4];
    float* out = (float*)d_out;

    ctc_fb2_kernel<<<Bn, 256, 0, stream>>>(logits, labels, input_length,
                                           label_length, mts, out);
}

// Round 11
// 143.194 us; speedup vs baseline: 1.7862x; 1.0819x over previous
//
#include <hip/hip_runtime.h>
#include <math.h>

// Problem constants: B=64, T=2000, V=29, L=200
#define Bn 64
#define Tn 2000
#define Vn 29
#define Ln 200
#define Sn 401              // 2L+1 lattice states
#define BLANKC 28
#define EPSF  1e-7f
#define CHUNK 128           // time steps of linear probs per LDS buffer
#define TSTR  132           // floats per symbol row (128 + pad, quad-aligned)
#define SENT  (-(1 << 20))  // exponent sentinel for all-zero lanes
#define LN2F  0.69314718055994531f

__device__ __forceinline__ float getc(const float4& v, int u) {
    return u == 0 ? v.x : u == 1 ? v.y : u == 2 ? v.z : v.w;
}
// Full-wave DPP shifts (gfx9-lineage): lane i <- lane i-1 (shr) / i+1 (shl),
// bound_ctrl=true zero-fills the boundary lane. Pure VALU — no DS pipe.
__device__ __forceinline__ float dpp_shr1_f(float x) {
    return __int_as_float(__builtin_amdgcn_update_dpp(
        0, __float_as_int(x), 0x138, 0xF, 0xF, true));
}
__device__ __forceinline__ int dpp_shr1_i(int x) {
    return __builtin_amdgcn_update_dpp(0, x, 0x138, 0xF, 0xF, true);
}
__device__ __forceinline__ float dpp_shl1_f(float x) {
    return __int_as_float(__builtin_amdgcn_update_dpp(
        0, __float_as_int(x), 0x130, 0xF, 0xF, true));
}
__device__ __forceinline__ int dpp_shl1_i(int x) {
    return __builtin_amdgcn_update_dpp(0, x, 0x130, 0xF, 0xF, true);
}
// 2^d restricted to d in [-126, 0]; anything else scales a flushed/zero
// operand and must return exactly 0 so no inf/NaN can be constructed.
__device__ __forceinline__ float dscale(int d) {
    return (d > 0 || d < -126) ? 0.f : __int_as_float((127 + d) << 23);
}

// ---------- forward round (4 steps). align -> prefetch -> DP -> fmax -> DPP sends -> renorm
#define ROUNDF(T0, PIN, POUT, PC, TOFFN) do {                                    \
  const int EeffF_ = zf_f ? SENT : E_f;                                          \
  const int EnF_   = max(EeffF_, Enb_f);                                         \
  const float sbF_ = dscale(Enb_f - EnF_), snF_ = dscale(EeffF_ - EnF_);         \
  float w[16];                                                                   \
  _Pragma("unroll") for (int k = 0; k < 8; ++k) w[k]     = nb_f[k] * sbF_;       \
  _Pragma("unroll") for (int k = 0; k < 8; ++k) w[8 + k] = a_f[k]  * snF_;       \
  { const int tf_ = (TOFFN) > (CHUNK-4) ? (CHUNK-4) : (TOFFN);                   \
    _Pragma("unroll") for (int kk = 0; kk < 7; ++kk)                             \
      POUT[kk] = *(const float4*)((PC) + soffF[kk] + tf_);                       \
    POUT[7] = *(const float4*)((PC) + BLANKC * TSTR + tf_); }                    \
  _Pragma("unroll") for (int u = 0; u < 4; ++u) {                                \
    const int t_ = (T0) + u;                                                     \
    if (t_ != 0 && t_ < TFe) {                                                   \
      _Pragma("unroll") for (int ii = 0; ii < 14 - 2 * u; ++ii) {                \
        const int i = 15 - ii;                                                   \
        if (i & 1) {                                                             \
          const int kk = (i - 3) >> 1;                                           \
          w[i] = (fmaf(skOdd[kk], w[i-2], w[i]) + w[i-1]) * getc(PIN[kk], u);    \
        } else {                                                                 \
          w[i] = (w[i] + w[i-1]) * getc(PIN[7], u);                              \
        } } } }                                                                  \
  float mxF_ = fmaxf(fmaxf(fmaxf(w[8],w[9]),fmaxf(w[10],w[11])),                 \
                     fmaxf(fmaxf(w[12],w[13]),fmaxf(w[14],w[15])));              \
  const bool z2F_ = !(mxF_ > 0.f);                                               \
  _Pragma("unroll") for (int k = 0; k < 8; ++k) nb_f[k] = dpp_shr1_f(w[8 + k]);  \
  Enb_f = dpp_shr1_i(z2F_ ? SENT : EnF_);                                        \
  if (lane == 0) Enb_f = SENT;                                                   \
  const int eF_ = ((__float_as_int(mxF_) >> 23) & 255) - 126;                    \
  const float rsF_ = __int_as_float((127 - eF_) << 23);                          \
  _Pragma("unroll") for (int k = 0; k < 8; ++k) a_f[k] = w[8 + k] * rsF_;        \
  E_f = EnF_ + eF_; zf_f = z2F_;                                                 \
} while (0)

// ---------- backward round (4 steps); lane owns w[0..7], lane+1 at w[8..15]
#define ROUNDB(S0, PIN, POUT, PC, TOFFN) do {                                    \
  const int EeffB_ = zf_b ? SENT : E_b;                                          \
  const int EnB_   = max(EeffB_, Enb_b);                                         \
  const float sbB_ = dscale(Enb_b - EnB_), snB_ = dscale(EeffB_ - EnB_);         \
  float w[16];                                                                   \
  _Pragma("unroll") for (int k = 0; k < 8; ++k) w[k]     = a_b[k]  * snB_;       \
  _Pragma("unroll") for (int k = 0; k < 8; ++k) w[8 + k] = nb_b[k] * sbB_;       \
  { const int tf_ = (TOFFN) > (CHUNK-4) ? (CHUNK-4) : (TOFFN);                   \
    _Pragma("unroll") for (int m = 0; m < 8; ++m)                                \
      POUT[m] = *(const float4*)((PC) + soffB[m] + tf_);                         \
    POUT[8] = *(const float4*)((PC) + BLANKC * TSTR + tf_); }                    \
  _Pragma("unroll") for (int u = 0; u < 4; ++u) {                                \
    const int s_ = (S0) + u;                                                     \
    if (s_ < TBe) {                                                              \
      float qq[16];                                                              \
      _Pragma("unroll") for (int j = 0; j < 16; ++j) {                           \
        if (j < 16 - 2 * u)                                                      \
          qq[j] = w[j] * ((j & 1) ? getc(PIN[(j-1)>>1], u) : getc(PIN[8], u));   \
        else qq[j] = 0.f; }                                                      \
      _Pragma("unroll") for (int i = 0; i < 14; ++i) {                           \
        if (i < 14 - 2 * u) {                                                    \
          if (i & 1) w[i] = fmaf(skB[(i-1)>>1], qq[i+2], qq[i]) + qq[i+1];       \
          else       w[i] = qq[i] + qq[i+1];                                     \
        } } } }                                                                  \
  float mxB_ = fmaxf(fmaxf(fmaxf(w[0],w[1]),fmaxf(w[2],w[3])),                   \
                     fmaxf(fmaxf(w[4],w[5]),fmaxf(w[6],w[7])));                  \
  const bool z2B_ = !(mxB_ > 0.f);                                               \
  _Pragma("unroll") for (int k = 0; k < 8; ++k) nb_b[k] = dpp_shl1_f(w[k]);      \
  Enb_b = dpp_shl1_i(z2B_ ? SENT : EnB_);                                        \
  if (lane == 63) Enb_b = SENT;                                                  \
  const int eB_ = ((__float_as_int(mxB_) >> 23) & 255) - 126;                    \
  const float rsB_ = __int_as_float((127 - eB_) << 23);                          \
  _Pragma("unroll") for (int k = 0; k < 8; ++k) a_b[k] = w[k] * rsB_;            \
  E_b = EnB_ + eB_; zf_b = z2B_;                                                 \
} while (0)

__global__ __launch_bounds__(256, 1)
void ctc_dpp_kernel(const float* __restrict__ logits,
                    const int*   __restrict__ labels,
                    const int*   __restrict__ input_length,
                    const int*   __restrict__ label_length,
                    const int*   __restrict__ mts_ptr,
                    float*       __restrict__ out)
{
    __shared__ __align__(16) float PFb[2][Vn * TSTR];   // fwd prob dbuf
    __shared__ __align__(16) float PBb[2][Vn * TSTR];   // bwd prob dbuf (time-reversed)

    const int b    = blockIdx.x;
    const int tid  = threadIdx.x;
    const int wid  = tid >> 6;    // 0: fwd DP, 1: bwd DP, 2: fwd stage, 3: bwd stage
    const int lane = tid & 63;
    const float* lg  = logits + (size_t)b * Tn * Vn;
    const int*   lab = labels + b * Ln;

    const int mts = *mts_ptr;
    const int ctc_len = (int)floorf((float)(input_length[b] * Tn) / (float)mts);
    const int tend = min(max(ctc_len, 1), Tn);
    const int tm   = (tend - 1) >> 1;      // meeting point
    const int TFe  = tm + 1;               // fwd consumes probs t in [0, TFe)
    const int TBe  = tend - 1 - tm;        // bwd consumes slots i=tend-1-t in [0, TBe)
    const int nchF = (TFe + CHUNK - 1) / CHUNK;
    const int nchB = (TBe + CHUNK - 1) / CHUNK;
    const int nch2 = max(nchF, nchB);

    // ---- fwd metadata ----
    int soffF[7]; float skOdd[7];
    #pragma unroll
    for (int kk = 0; kk < 7; ++kk) {
        const int s = 8 * lane - 5 + 2 * kk;
        int e = BLANKC; float sk = 0.f;
        if (s >= 0 && s < Sn) {
            const int li = (s - 1) >> 1;
            e = lab[li];
            if (s >= 3 && e != lab[li - 1]) sk = 1.f;
        }
        soffF[kk] = e * TSTR; skOdd[kk] = sk;
    }
    // ---- bwd metadata ----
    int soffB[8]; float skB[7];
    #pragma unroll
    for (int m = 0; m < 8; ++m) {
        const int s = 8 * lane + 2 * m + 1;
        soffB[m] = ((s < Sn) ? lab[(s - 1) >> 1] : BLANKC) * TSTR;
    }
    #pragma unroll
    for (int m = 0; m < 7; ++m) {
        const int s = 8 * lane + 2 * m + 3;
        float sk = 0.f;
        if (s >= 3 && s < Sn) {
            const int li = (s - 1) >> 1;
            if (lab[li] != lab[li - 1]) sk = 1.f;
        }
        skB[m] = sk;
    }

    // staging: linear probs (softmax + eps), transposed [v][slot]
    auto srow = [&](const float* row, float* Pb, int i) {
        float x[Vn]; float mm = -INFINITY;
        #pragma unroll
        for (int v = 0; v < Vn; ++v) { x[v] = row[v]; mm = fmaxf(mm, x[v]); }
        float z = 0.f;
        #pragma unroll
        for (int v = 0; v < Vn; ++v) { x[v] = __expf(x[v] - mm); z += x[v]; }
        const float rz = 1.0f / z;
        #pragma unroll
        for (int v = 0; v < Vn; ++v) Pb[v * TSTR + i] = x[v] * rz + EPSF;
    };
    auto stageF = [&](int c) {
        const int base = c * CHUNK;
        const int fill = min(CHUNK, TFe - base);
        float* Pb = PFb[c & 1];
        for (int i = lane; i < fill; i += 64)
            srow(lg + (size_t)(base + i) * Vn, Pb, i);
    };
    auto stageB = [&](int c) {
        const int base = c * CHUNK;
        const int fill = min(CHUNK, TBe - base);
        float* Pb = PBb[c & 1];
        for (int i = lane; i < fill; i += 64)
            srow(lg + (size_t)(tend - 1 - (base + i)) * Vn, Pb, i);
    };

    if (wid == 2) stageF(0);
    if (wid == 3 && TBe > 0) stageB(0);
    __syncthreads();

    // per-lane BFP state
    float a_f[8] = {0.f,0.f,0.f,0.f,0.f,0.f,0.f,0.f};
    float a_b[8] = {0.f,0.f,0.f,0.f,0.f,0.f,0.f,0.f};
    float nb_f[8], nb_b[8];
    int   E_f = 0, Enb_f = SENT, E_b = 0, Enb_b = SENT;
    bool  zf_f = true, zf_b = true;
    float4 qAf[8], qBf[8], qAb[9], qBb[9];

    if (wid == 0) {
        __builtin_amdgcn_s_setprio(1);
        if (lane == 0) {
            a_f[0] = PFb[0][BLANKC * TSTR];
            a_f[1] = PFb[0][soffF[3]];      // lane0 kk=3 -> s=1 -> lab[0]
        }
        zf_f = (lane != 0);
        #pragma unroll
        for (int k = 0; k < 8; ++k) nb_f[k] = dpp_shr1_f(a_f[k]);
        Enb_f = dpp_shr1_i(zf_f ? SENT : 0);
        if (lane == 0) Enb_f = SENT;
    } else if (wid == 1) {
        __builtin_amdgcn_s_setprio(1);
        const int ll = label_length[b];
        const int s1 = 2 * ll, s2 = max(2 * ll - 1, 0);
        #pragma unroll
        for (int k = 0; k < 8; ++k) {
            const int s = 8 * lane + k;
            a_b[k] = (s == s1 || s == s2) ? 0.5f : 0.f;   // beta = 1 (0.5*2^1)
        }
        E_b  = 1;
        zf_b = !(((s1 >> 3) == lane) || ((s2 >> 3) == lane));
        #pragma unroll
        for (int k = 0; k < 8; ++k) nb_b[k] = dpp_shl1_f(a_b[k]);
        Enb_b = dpp_shl1_i(zf_b ? SENT : E_b);
        if (lane == 63) Enb_b = SENT;
    }

    for (int c = 0; c < nch2; ++c) {
        if (wid == 2) {
            if (c + 1 < nchF) stageF(c + 1);
        } else if (wid == 3) {
            if (c + 1 < nchB) stageB(c + 1);
        } else if (wid == 0) {
            if (c < nchF) {
                float* Pc = PFb[c & 1];
                const int rbase = c * CHUNK;
                const int rcnt  = min(CHUNK, TFe - rbase);
                const int nr    = (rcnt + 3) >> 2;
                #pragma unroll
                for (int kk = 0; kk < 7; ++kk)
                    qAf[kk] = *(const float4*)(Pc + soffF[kk]);
                qAf[7] = *(const float4*)(Pc + BLANKC * TSTR);
                for (int jj = 0; jj < nr; jj += 2) {
                    ROUNDF(rbase + 4 * jj,       qAf, qBf, Pc, 4 * (jj + 1));
                    ROUNDF(rbase + 4 * (jj + 1), qBf, qAf, Pc, 4 * (jj + 2));
                }
            }
        } else {
            if (c < nchB) {
                float* Pc = PBb[c & 1];
                const int sbase = c * CHUNK;
                const int rcnt  = min(CHUNK, TBe - sbase);
                const int nr    = (rcnt + 3) >> 2;
                #pragma unroll
                for (int m = 0; m < 8; ++m)
                    qAb[m] = *(const float4*)(Pc + soffB[m]);
                qAb[8] = *(const float4*)(Pc + BLANKC * TSTR);
                for (int jj = 0; jj < nr; jj += 2) {
                    ROUNDB(sbase + 4 * jj,       qAb, qBb, Pc, 4 * (jj + 1));
                    ROUNDB(sbase + 4 * (jj + 1), qBb, qAb, Pc, 4 * (jj + 2));
                }
            }
        }
        __syncthreads();
    }

    // readout: sum_s alpha_tm[s] * beta_tm[s]  (AF/EL alias the prob buffers)
    float* AFa = PFb[0];
    int*   ELa = (int*)(PFb[0] + 512);
    float* AFb = PBb[0];
    int*   ELb = (int*)(PBb[0] + 512);

    if (wid == 0) {
        #pragma unroll
        for (int k = 0; k < 8; ++k) AFa[lane * 8 + k] = a_f[k];
        ELa[lane] = zf_f ? SENT : E_f;
    } else if (wid == 1) {
        #pragma unroll
        for (int k = 0; k < 8; ++k) AFb[lane * 8 + k] = a_b[k];
        ELb[lane] = zf_b ? SENT : E_b;
    }
    __syncthreads();

    if (wid == 0) {
        float v = 0.f;
        #pragma unroll
        for (int k = 0; k < 8; ++k)
            v = fmaf(AFa[lane * 8 + k], AFb[lane * 8 + k], v);
        const int el  = ELa[lane] + ELb[lane];
        const bool val = (v > 0.f);
        int em = val ? el : (SENT * 2);
        #pragma unroll
        for (int off = 1; off < 64; off <<= 1)
            em = max(em, __shfl_xor(em, off, 64));
        float sv = val ? ldexpf(v, el - em) : 0.f;
        #pragma unroll
        for (int off = 1; off < 64; off <<= 1)
            sv += __shfl_xor(sv, off, 64);
        if (lane == 0) out[b] = -(__logf(sv) + (float)em * LN2F);
    }
}

extern "C" void kernel_launch(void* const* d_in, const int* in_sizes, int n_in,
                              void* d_out, int out_size, void* d_ws, size_t ws_size,
                              hipStream_t stream) {
    const float* logits       = (const float*)d_in[0];
    const int*   labels       = (const int*)d_in[1];
    const int*   input_length = (const int*)d_in[2];
    const int*   label_length = (const int*)d_in[3];
    const int*   mts          = (const int*)d_in[4];
    float* out = (float*)d_out;

    ctc_dpp_kernel<<<Bn, 256, 0, stream>>>(logits, labels, input_length,
                                           label_length, mts, out);
}

// Round 12
// 98.629 us; speedup vs baseline: 2.5933x; 1.4519x over previous
//
#include <hip/hip_runtime.h>
#include <math.h>

// Problem constants: B=64, T=2000, V=29, L=200
#define Bn 64
#define Tn 2000
#define Vn 29
#define Ln 200
#define Sn 401              // 2L+1 lattice states
#define BLANKC 28
#define EPSF  1e-7f
#define CHUNK 128           // time steps of linear probs per LDS buffer
#define TSTR  132           // floats per symbol row (128 + pad, quad-aligned)
#define SENT  (-(1 << 20))  // exponent sentinel for all-zero lanes
#define LN2F  0.69314718055994531f

__device__ __forceinline__ float getc(const float4& v, int u) {
    return u == 0 ? v.x : u == 1 ? v.y : u == 2 ? v.z : v.w;
}
// Full-wave DPP shifts: lane i <- lane i-1 (shr) / i+1 (shl); bound_ctrl
// zero-fills the boundary lane. Pure VALU — no DS pipe. (HW-verified R11.)
__device__ __forceinline__ float dpp_shr1_f(float x) {
    return __int_as_float(__builtin_amdgcn_update_dpp(
        0, __float_as_int(x), 0x138, 0xF, 0xF, true));
}
__device__ __forceinline__ int dpp_shr1_i(int x) {
    return __builtin_amdgcn_update_dpp(0, x, 0x138, 0xF, 0xF, true);
}
__device__ __forceinline__ float dpp_shl1_f(float x) {
    return __int_as_float(__builtin_amdgcn_update_dpp(
        0, __float_as_int(x), 0x130, 0xF, 0xF, true));
}
__device__ __forceinline__ int dpp_shl1_i(int x) {
    return __builtin_amdgcn_update_dpp(0, x, 0x130, 0xF, 0xF, true);
}
// 2^d restricted to d in [-126, 0]; anything else scales a flushed/zero
// operand and must return exactly 0 so no inf/NaN can be constructed.
__device__ __forceinline__ float dscale(int d) {
    return (d > 0 || d < -126) ? 0.f : __int_as_float((127 + d) << 23);
}

// ---- shared round pieces ----
#define ALIGNF_                                                                  \
  const int EeffF_ = zf_f ? SENT : E_f;                                          \
  const int EnF_   = max(EeffF_, Enb_f);                                         \
  const float sbF_ = dscale(Enb_f - EnF_), snF_ = dscale(EeffF_ - EnF_);         \
  float w[16];                                                                   \
  _Pragma("unroll") for (int k = 0; k < 8; ++k) w[k]     = nb_f[k] * sbF_;       \
  _Pragma("unroll") for (int k = 0; k < 8; ++k) w[8 + k] = a_f[k]  * snF_;

#define PREFF_(POUT, PC, TOFFN)                                                  \
  { const int tf_ = (TOFFN) > (CHUNK-4) ? (CHUNK-4) : (TOFFN);                   \
    _Pragma("unroll") for (int kk = 0; kk < 7; ++kk)                             \
      POUT[kk] = *(const float4*)((PC) + soffF[kk] + tf_);                       \
    POUT[7] = *(const float4*)((PC) + BLANKC * TSTR + tf_); }

#define STEPF_(PIN, u)                                                           \
  _Pragma("unroll") for (int ii = 0; ii < 14 - 2 * (u); ++ii) {                  \
    const int i = 15 - ii;                                                       \
    if (i & 1) {                                                                 \
      const int kk = (i - 3) >> 1;                                               \
      w[i] = (fmaf(skOdd[kk], w[i-2], w[i]) + w[i-1]) * getc(PIN[kk], u);        \
    } else {                                                                     \
      w[i] = (w[i] + w[i-1]) * getc(PIN[7], u);                                  \
    } }

#define FINF_                                                                    \
  float mxF_ = fmaxf(fmaxf(fmaxf(w[8],w[9]),fmaxf(w[10],w[11])),                 \
                     fmaxf(fmaxf(w[12],w[13]),fmaxf(w[14],w[15])));              \
  const bool z2F_ = !(mxF_ > 0.f);                                               \
  _Pragma("unroll") for (int k = 0; k < 8; ++k) nb_f[k] = dpp_shr1_f(w[8 + k]);  \
  Enb_f = dpp_shr1_i(z2F_ ? SENT : EnF_);                                        \
  if (lane == 0) Enb_f = SENT;                                                   \
  const int eF_ = ((__float_as_int(mxF_) >> 23) & 255) - 126;                    \
  const float rsF_ = __int_as_float((127 - eF_) << 23);                          \
  _Pragma("unroll") for (int k = 0; k < 8; ++k) a_f[k] = w[8 + k] * rsF_;        \
  E_f = EnF_ + eF_; zf_f = z2F_;

// guarded round (first/tail): step valid iff t != 0 && t < TFe
#define ROUNDF(T0, PIN, POUT, PC, TOFFN) do {                                    \
  ALIGNF_                                                                        \
  PREFF_(POUT, PC, TOFFN)                                                        \
  _Pragma("unroll") for (int u = 0; u < 4; ++u) {                                \
    const int t_ = (T0) + u;                                                     \
    if (t_ != 0 && t_ < TFe) { STEPF_(PIN, u) }                                  \
  }                                                                              \
  FINF_                                                                          \
} while (0)

// branchless round: all 4 steps valid
#define ROUNDF_NG(PIN, POUT, PC, TOFFN) do {                                     \
  ALIGNF_                                                                        \
  PREFF_(POUT, PC, TOFFN)                                                        \
  STEPF_(PIN, 0) STEPF_(PIN, 1) STEPF_(PIN, 2) STEPF_(PIN, 3)                    \
  FINF_                                                                          \
} while (0)

#define ALIGNB_                                                                  \
  const int EeffB_ = zf_b ? SENT : E_b;                                          \
  const int EnB_   = max(EeffB_, Enb_b);                                         \
  const float sbB_ = dscale(Enb_b - EnB_), snB_ = dscale(EeffB_ - EnB_);         \
  float w[16];                                                                   \
  _Pragma("unroll") for (int k = 0; k < 8; ++k) w[k]     = a_b[k]  * snB_;       \
  _Pragma("unroll") for (int k = 0; k < 8; ++k) w[8 + k] = nb_b[k] * sbB_;

#define PREFB_(POUT, PC, TOFFN)                                                  \
  { const int tf_ = (TOFFN) > (CHUNK-4) ? (CHUNK-4) : (TOFFN);                   \
    _Pragma("unroll") for (int m = 0; m < 8; ++m)                                \
      POUT[m] = *(const float4*)((PC) + soffB[m] + tf_);                         \
    POUT[8] = *(const float4*)((PC) + BLANKC * TSTR + tf_); }

#define STEPB_(PIN, u)                                                           \
  { float qq[16];                                                                \
    _Pragma("unroll") for (int j = 0; j < 16; ++j) {                             \
      if (j < 16 - 2 * (u))                                                      \
        qq[j] = w[j] * ((j & 1) ? getc(PIN[(j-1)>>1], u) : getc(PIN[8], u));     \
      else qq[j] = 0.f; }                                                        \
    _Pragma("unroll") for (int i = 0; i < 14; ++i) {                             \
      if (i < 14 - 2 * (u)) {                                                    \
        if (i & 1) w[i] = fmaf(skB[(i-1)>>1], qq[i+2], qq[i]) + qq[i+1];         \
        else       w[i] = qq[i] + qq[i+1];                                       \
      } } }

#define FINB_                                                                    \
  float mxB_ = fmaxf(fmaxf(fmaxf(w[0],w[1]),fmaxf(w[2],w[3])),                   \
                     fmaxf(fmaxf(w[4],w[5]),fmaxf(w[6],w[7])));                  \
  const bool z2B_ = !(mxB_ > 0.f);                                               \
  _Pragma("unroll") for (int k = 0; k < 8; ++k) nb_b[k] = dpp_shl1_f(w[k]);      \
  Enb_b = dpp_shl1_i(z2B_ ? SENT : EnB_);                                        \
  if (lane == 63) Enb_b = SENT;                                                  \
  const int eB_ = ((__float_as_int(mxB_) >> 23) & 255) - 126;                    \
  const float rsB_ = __int_as_float((127 - eB_) << 23);                          \
  _Pragma("unroll") for (int k = 0; k < 8; ++k) a_b[k] = w[k] * rsB_;            \
  E_b = EnB_ + eB_; zf_b = z2B_;

#define ROUNDB(S0, PIN, POUT, PC, TOFFN) do {                                    \
  ALIGNB_                                                                        \
  PREFB_(POUT, PC, TOFFN)                                                        \
  _Pragma("unroll") for (int u = 0; u < 4; ++u) {                                \
    const int s_ = (S0) + u;                                                     \
    if (s_ < TBe) { STEPB_(PIN, u) }                                             \
  }                                                                              \
  FINB_                                                                          \
} while (0)

#define ROUNDB_NG(PIN, POUT, PC, TOFFN) do {                                     \
  ALIGNB_                                                                        \
  PREFB_(POUT, PC, TOFFN)                                                        \
  STEPB_(PIN, 0) STEPB_(PIN, 1) STEPB_(PIN, 2) STEPB_(PIN, 3)                    \
  FINB_                                                                          \
} while (0)

__global__ __launch_bounds__(256, 1)
void ctc_ng_kernel(const float* __restrict__ logits,
                   const int*   __restrict__ labels,
                   const int*   __restrict__ input_length,
                   const int*   __restrict__ label_length,
                   const int*   __restrict__ mts_ptr,
                   float*       __restrict__ out)
{
    __shared__ __align__(16) float PFb[2][Vn * TSTR];   // fwd prob dbuf
    __shared__ __align__(16) float PBb[2][Vn * TSTR];   // bwd prob dbuf (time-reversed)

    const int b    = blockIdx.x;
    const int tid  = threadIdx.x;
    const int wid  = tid >> 6;    // 0: fwd DP, 1: bwd DP, 2: fwd stage, 3: bwd stage
    const int lane = tid & 63;
    const float* lg  = logits + (size_t)b * Tn * Vn;
    const int*   lab = labels + b * Ln;

    const int mts = *mts_ptr;
    const int ctc_len = (int)floorf((float)(input_length[b] * Tn) / (float)mts);
    const int tend = min(max(ctc_len, 1), Tn);
    const int tm   = (tend - 1) >> 1;      // meeting point
    const int TFe  = tm + 1;               // fwd consumes probs t in [0, TFe)
    const int TBe  = tend - 1 - tm;        // bwd consumes slots i=tend-1-t in [0, TBe)
    const int nchF = (TFe + CHUNK - 1) / CHUNK;
    const int nchB = (TBe + CHUNK - 1) / CHUNK;
    const int nch2 = max(nchF, nchB);

    // ---- fwd metadata ----
    int soffF[7]; float skOdd[7];
    #pragma unroll
    for (int kk = 0; kk < 7; ++kk) {
        const int s = 8 * lane - 5 + 2 * kk;
        int e = BLANKC; float sk = 0.f;
        if (s >= 0 && s < Sn) {
            const int li = (s - 1) >> 1;
            e = lab[li];
            if (s >= 3 && e != lab[li - 1]) sk = 1.f;
        }
        soffF[kk] = e * TSTR; skOdd[kk] = sk;
    }
    // ---- bwd metadata ----
    int soffB[8]; float skB[7];
    #pragma unroll
    for (int m = 0; m < 8; ++m) {
        const int s = 8 * lane + 2 * m + 1;
        soffB[m] = ((s < Sn) ? lab[(s - 1) >> 1] : BLANKC) * TSTR;
    }
    #pragma unroll
    for (int m = 0; m < 7; ++m) {
        const int s = 8 * lane + 2 * m + 3;
        float sk = 0.f;
        if (s >= 3 && s < Sn) {
            const int li = (s - 1) >> 1;
            if (lab[li] != lab[li - 1]) sk = 1.f;
        }
        skB[m] = sk;
    }

    // staging: linear probs (softmax + eps), transposed [v][slot]
    auto srow = [&](const float* row, float* Pb, int i) {
        float x[Vn]; float mm = -INFINITY;
        #pragma unroll
        for (int v = 0; v < Vn; ++v) { x[v] = row[v]; mm = fmaxf(mm, x[v]); }
        float z = 0.f;
        #pragma unroll
        for (int v = 0; v < Vn; ++v) { x[v] = __expf(x[v] - mm); z += x[v]; }
        const float rz = 1.0f / z;
        #pragma unroll
        for (int v = 0; v < Vn; ++v) Pb[v * TSTR + i] = x[v] * rz + EPSF;
    };
    auto stageF = [&](int c) {
        const int base = c * CHUNK;
        const int fill = min(CHUNK, TFe - base);
        float* Pb = PFb[c & 1];
        for (int i = lane; i < fill; i += 64)
            srow(lg + (size_t)(base + i) * Vn, Pb, i);
    };
    auto stageB = [&](int c) {
        const int base = c * CHUNK;
        const int fill = min(CHUNK, TBe - base);
        float* Pb = PBb[c & 1];
        for (int i = lane; i < fill; i += 64)
            srow(lg + (size_t)(tend - 1 - (base + i)) * Vn, Pb, i);
    };

    if (wid == 2) stageF(0);
    if (wid == 3 && TBe > 0) stageB(0);
    __syncthreads();

    // per-lane BFP state
    float a_f[8] = {0.f,0.f,0.f,0.f,0.f,0.f,0.f,0.f};
    float a_b[8] = {0.f,0.f,0.f,0.f,0.f,0.f,0.f,0.f};
    float nb_f[8], nb_b[8];
    int   E_f = 0, Enb_f = SENT, E_b = 0, Enb_b = SENT;
    bool  zf_f = true, zf_b = true;
    float4 qAf[8], qBf[8], qAb[9], qBb[9];

    if (wid == 0) {
        __builtin_amdgcn_s_setprio(1);
        if (lane == 0) {
            a_f[0] = PFb[0][BLANKC * TSTR];
            a_f[1] = PFb[0][soffF[3]];      // lane0 kk=3 -> s=1 -> lab[0]
        }
        zf_f = (lane != 0);
        #pragma unroll
        for (int k = 0; k < 8; ++k) nb_f[k] = dpp_shr1_f(a_f[k]);
        Enb_f = dpp_shr1_i(zf_f ? SENT : 0);
        if (lane == 0) Enb_f = SENT;
    } else if (wid == 1) {
        __builtin_amdgcn_s_setprio(1);
        const int ll = label_length[b];
        const int s1 = 2 * ll, s2 = max(2 * ll - 1, 0);
        #pragma unroll
        for (int k = 0; k < 8; ++k) {
            const int s = 8 * lane + k;
            a_b[k] = (s == s1 || s == s2) ? 0.5f : 0.f;   // beta = 1 (0.5*2^1)
        }
        E_b  = 1;
        zf_b = !(((s1 >> 3) == lane) || ((s2 >> 3) == lane));
        #pragma unroll
        for (int k = 0; k < 8; ++k) nb_b[k] = dpp_shl1_f(a_b[k]);
        Enb_b = dpp_shl1_i(zf_b ? SENT : E_b);
        if (lane == 63) Enb_b = SENT;
    }

    for (int c = 0; c < nch2; ++c) {
        if (wid == 2) {
            if (c + 1 < nchF) stageF(c + 1);
        } else if (wid == 3) {
            if (c + 1 < nchB) stageB(c + 1);
        } else if (wid == 0) {
            if (c < nchF) {
                float* Pc = PFb[c & 1];
                const int rbase = c * CHUNK;
                const int rcnt  = min(CHUNK, TFe - rbase);
                const int nr    = (rcnt + 3) >> 2;          // rounds this chunk
                const int nfull = min((TFe - rbase) >> 2, nr); // branchless-safe rounds
                #pragma unroll
                for (int kk = 0; kk < 7; ++kk)
                    qAf[kk] = *(const float4*)(Pc + soffF[kk]);
                qAf[7] = *(const float4*)(Pc + BLANKC * TSTR);

                int jj = 0;
                if (c == 0) {   // first pair guarded (contains t=0)
                    ROUNDF(0, qAf, qBf, Pc, 4);
                    ROUNDF(4, qBf, qAf, Pc, 8);
                    jj = 2;
                }
                for (; jj + 2 <= nfull; jj += 2) {   // hot path: branchless
                    ROUNDF_NG(qAf, qBf, Pc, 4 * (jj + 1));
                    ROUNDF_NG(qBf, qAf, Pc, 4 * (jj + 2));
                }
                for (; jj < nr; jj += 2) {           // tail pair guarded
                    ROUNDF(rbase + 4 * jj,       qAf, qBf, Pc, 4 * (jj + 1));
                    ROUNDF(rbase + 4 * (jj + 1), qBf, qAf, Pc, 4 * (jj + 2));
                }
            }
        } else {
            if (c < nchB) {
                float* Pc = PBb[c & 1];
                const int sbase = c * CHUNK;
                const int rcnt  = min(CHUNK, TBe - sbase);
                const int nr    = (rcnt + 3) >> 2;
                const int nfull = min((TBe - sbase) >> 2, nr);
                #pragma unroll
                for (int m = 0; m < 8; ++m)
                    qAb[m] = *(const float4*)(Pc + soffB[m]);
                qAb[8] = *(const float4*)(Pc + BLANKC * TSTR);

                int jj = 0;
                for (; jj + 2 <= nfull; jj += 2) {   // hot path: branchless
                    ROUNDB_NG(qAb, qBb, Pc, 4 * (jj + 1));
                    ROUNDB_NG(qBb, qAb, Pc, 4 * (jj + 2));
                }
                for (; jj < nr; jj += 2) {           // tail pair guarded
                    ROUNDB(sbase + 4 * jj,       qAb, qBb, Pc, 4 * (jj + 1));
                    ROUNDB(sbase + 4 * (jj + 1), qBb, qAb, Pc, 4 * (jj + 2));
                }
            }
        }
        __syncthreads();
    }

    // readout: sum_s alpha_tm[s] * beta_tm[s]  (AF/EL alias the prob buffers)
    float* AFa = PFb[0];
    int*   ELa = (int*)(PFb[0] + 512);
    float* AFb = PBb[0];
    int*   ELb = (int*)(PBb[0] + 512);

    if (wid == 0) {
        #pragma unroll
        for (int k = 0; k < 8; ++k) AFa[lane * 8 + k] = a_f[k];
        ELa[lane] = zf_f ? SENT : E_f;
    } else if (wid == 1) {
        #pragma unroll
        for (int k = 0; k < 8; ++k) AFb[lane * 8 + k] = a_b[k];
        ELb[lane] = zf_b ? SENT : E_b;
    }
    __syncthreads();

    if (wid == 0) {
        float v = 0.f;
        #pragma unroll
        for (int k = 0; k < 8; ++k)
            v = fmaf(AFa[lane * 8 + k], AFb[lane * 8 + k], v);
        const int el  = ELa[lane] + ELb[lane];
        const bool val = (v > 0.f);
        int em = val ? el : (SENT * 2);
        #pragma unroll
        for (int off = 1; off < 64; off <<= 1)
            em = max(em, __shfl_xor(em, off, 64));
        float sv = val ? ldexpf(v, el - em) : 0.f;
        #pragma unroll
        for (int off = 1; off < 64; off <<= 1)
            sv += __shfl_xor(sv, off, 64);
        if (lane == 0) out[b] = -(__logf(sv) + (float)em * LN2F);
    }
}

extern "C" void kernel_launch(void* const* d_in, const int* in_sizes, int n_in,
                              void* d_out, int out_size, void* d_ws, size_t ws_size,
                              hipStream_t stream) {
    const float* logits       = (const float*)d_in[0];
    const int*   labels       = (const int*)d_in[1];
    const int*   input_length = (const int*)d_in[2];
    const int*   label_length = (const int*)d_in[3];
    const int*   mts          = (const int*)d_in[4];
    float* out = (float*)d_out;

    ctc_ng_kernel<<<Bn, 256, 0, stream>>>(logits, labels, input_length,
                                          label_length, mts, out);
}